// Round 5
// baseline (176.216 us; speedup 1.0000x reference)
//
#include <hip/hip_runtime.h>

typedef __attribute__((ext_vector_type(8))) short short8;
typedef __attribute__((ext_vector_type(4))) unsigned short ushort4v;
typedef __attribute__((ext_vector_type(4))) int int4v;
typedef __attribute__((ext_vector_type(4))) float f32x4;

#define Mdim 64
#define Kdim 8192
#define Ndim 8192
#define GRP 128
#define NGRP 64
#define KSPLIT 8
#define NG2 (NGRP / KSPLIT)   // 8 groups per block
#define BN 128                // 8 waves x 16 private cols

__device__ __forceinline__ unsigned short f2bf(float f) {
    unsigned int u = __builtin_bit_cast(unsigned int, f);
    u += 0x7FFFu + ((u >> 16) & 1u);   // round-to-nearest-even
    return (unsigned short)(u >> 16);
}
__device__ __forceinline__ float bf2f(unsigned short h) {
    unsigned int u = ((unsigned int)h) << 16;
    return __builtin_bit_cast(float, u);
}

// Build xh/xl (hi/lo bf16 split of x) and per-(group,m) sums xsum[g][m].
__global__ void prep_kernel(const float* __restrict__ x,
                            unsigned short* __restrict__ xh,
                            unsigned short* __restrict__ xl,
                            float* __restrict__ xsum) {
    const int tid = threadIdx.x;
    const int u = blockIdx.x * 8 + (tid >> 5);
    const int g = u & (NGRP - 1);
    const int m = u >> 6;
    const int lane = tid & 31;
    const int k = g * GRP + lane * 4;
    f32x4 v = *(const f32x4*)(x + (size_t)m * Kdim + k);
    ushort4v hv, lv;
    float s = 0.f;
#pragma unroll
    for (int i = 0; i < 4; ++i) {
        unsigned short h = f2bf(v[i]);
        hv[i] = h;
        lv[i] = f2bf(v[i] - bf2f(h));
        s += v[i];
    }
    *(ushort4v*)(xh + (size_t)m * Kdim + k) = hv;
    *(ushort4v*)(xl + (size_t)m * Kdim + k) = lv;
#pragma unroll
    for (int off = 16; off > 0; off >>= 1) s += __shfl_down(s, off, 32);
    if (lane == 0) xsum[g * Mdim + m] = s;
}

// Main: 512 blocks = 64 n-tiles x 8 k-splits. 512 threads = 8 waves; each wave
// owns a PRIVATE 16-col strip and computes 64x16 output (4 m-frags). q staged
// in wave-private LDS (4 KB, single-buffered, XOR-16B swizzle) -> NO barriers
// in the k-loop. x A-frags load straight from global (L1/L2-hot).
__launch_bounds__(512, 4)
__global__ void qlin_kernel(const unsigned short* __restrict__ xh,
                            const unsigned short* __restrict__ xl,
                            const int* __restrict__ qw,
                            const float* __restrict__ scales,
                            const float* __restrict__ zeros,
                            const float* __restrict__ xsum,
                            float* __restrict__ pout) {
    __shared__ unsigned short lq[8][16 * 128];   // per-wave 4 KB, bf16 [col16][k128] swizzled

    const int tid = threadIdx.x;
    const int kh = blockIdx.x & (KSPLIT - 1);
    const int n0 = (blockIdx.x >> 3) * BN;
    const int g0 = kh * NG2;

    const int w = tid >> 6;
    const int l = tid & 63;
    const int lcol = l & 15;      // MFMA col / A-row lane
    const int lhi = l >> 4;       // 0..3
    const int kq = l >> 2;        // staging: k-octet 0..15
    const int cq = l & 3;         // staging: col-quad 0..3
    const int nw = n0 + w * 16;   // this wave's col base

    unsigned short* myq = &lq[w][0];

    int4v qv[8];                  // staging regs: 8 k-rows x 4 cols of int q

    auto LOADQ = [&](int g) {     // g relative to g0
        const size_t kb = (size_t)(g0 + g) * GRP + kq * 8;
        const int nc = nw + cq * 4;
#pragma unroll
        for (int j = 0; j < 8; ++j)
            qv[j] = __builtin_nontemporal_load((const int4v*)(qw + (kb + j) * Ndim + nc));
    };
    auto WRITEQ = [&]() {         // exact int->bf16 (truncate; |q|<=128), b128 swizzled writes
#pragma unroll
        for (int i = 0; i < 4; ++i) {
            int4v pk;
#pragma unroll
            for (int t = 0; t < 4; ++t) {
                unsigned lo = __builtin_bit_cast(unsigned, (float)qv[2 * t][i]) >> 16;
                unsigned hi = __builtin_bit_cast(unsigned, (float)qv[2 * t + 1][i]) & 0xFFFF0000u;
                pk[t] = (int)(lo | hi);
            }
            const int r = cq * 4 + i;
            *(int4v*)&myq[r * 128 + ((8 * kq) ^ ((r & 7) << 3))] = pk;
        }
    };

    f32x4 acc[4], p[4];
#pragma unroll
    for (int mf = 0; mf < 4; ++mf) acc[mf] = {0.f, 0.f, 0.f, 0.f};

    LOADQ(0);
    WRITEQ();

    for (int g = 0; g < NG2; ++g) {
        // B-frags for group g out of private LDS into regs (frees the buffer)
        short8 bq[4];
#pragma unroll
        for (int ks = 0; ks < 4; ++ks)
            bq[ks] = *(const short8*)&myq[lcol * 128 + ((ks * 32 + lhi * 8) ^ ((lcol & 7) << 3))];

        if (g + 1 < NG2) LOADQ(g + 1);   // next group's q in flight during MFMA

        const size_t ka = (size_t)(g0 + g) * GRP + lhi * 8;
#pragma unroll
        for (int mf = 0; mf < 4; ++mf) {
            p[mf] = {0.f, 0.f, 0.f, 0.f};
            const size_t xoff = (size_t)(mf * 16 + lcol) * Kdim + ka;
#pragma unroll
            for (int ks = 0; ks < 4; ++ks) {
                short8 ah = *(const short8*)(xh + xoff + ks * 32);
                short8 al = *(const short8*)(xl + xoff + ks * 32);
                p[mf] = __builtin_amdgcn_mfma_f32_16x16x32_bf16(ah, bq[ks], p[mf], 0, 0, 0);
                p[mf] = __builtin_amdgcn_mfma_f32_16x16x32_bf16(al, bq[ks], p[mf], 0, 0, 0);
            }
        }

        // per-group fold in fp32 (s/z/xsum are tiny L1/L2-hot tables)
        const float s = scales[(size_t)(g0 + g) * Ndim + nw + lcol];
        const float z = zeros[(size_t)(g0 + g) * Ndim + nw + lcol];
#pragma unroll
        for (int mf = 0; mf < 4; ++mf) {
            f32x4 xs = *(const f32x4*)(xsum + (g0 + g) * Mdim + mf * 16 + lhi * 4);
#pragma unroll
            for (int r = 0; r < 4; ++r)
                acc[mf][r] += s * (p[mf][r] - z * xs[r]);
        }

        if (g + 1 < NG2) WRITEQ();       // stage next group (wave-private, no barrier)
    }

    const size_t ob = (size_t)kh * Mdim * Ndim;
#pragma unroll
    for (int mf = 0; mf < 4; ++mf)
#pragma unroll
        for (int r = 0; r < 4; ++r)
            pout[ob + (size_t)(mf * 16 + lhi * 4 + r) * Ndim + nw + lcol] = acc[mf][r];
}

// out = sum of KSPLIT partials + bias
__global__ void reduce_kernel(const float* __restrict__ pout,
                              const float* __restrict__ bias,
                              float* __restrict__ out) {
    const size_t e = ((size_t)blockIdx.x * 256 + threadIdx.x) * 4;
    const int n = (int)(e & (Ndim - 1));
    f32x4 a = *(const f32x4*)(bias + n);
#pragma unroll
    for (int s = 0; s < KSPLIT; ++s) {
        f32x4 ppart = *(const f32x4*)(pout + (size_t)s * Mdim * Ndim + e);
#pragma unroll
        for (int r = 0; r < 4; ++r) a[r] += ppart[r];
    }
    *(f32x4*)(out + e) = a;
}

extern "C" void kernel_launch(void* const* d_in, const int* in_sizes, int n_in,
                              void* d_out, int out_size, void* d_ws, size_t ws_size,
                              hipStream_t stream) {
    const float* x = (const float*)d_in[0];
    const int* qw = (const int*)d_in[1];
    const float* scales = (const float*)d_in[2];
    const float* zeros = (const float*)d_in[3];
    const float* bias = (const float*)d_in[4];

    unsigned short* xh = (unsigned short*)d_ws;
    unsigned short* xl = xh + (size_t)Mdim * Kdim;
    float* xsum = (float*)(xl + (size_t)Mdim * Kdim);
    float* pout = xsum + NGRP * Mdim;
    float* out = (float*)d_out;

    prep_kernel<<<512, 256, 0, stream>>>(x, xh, xl, xsum);
    qlin_kernel<<<(Ndim / BN) * KSPLIT, 512, 0, stream>>>(xh, xl, qw, scales, zeros, xsum, pout);
    reduce_kernel<<<(Mdim * Ndim / 4) / 256, 256, 0, stream>>>(pout, bias, out);
}